// Round 1
// baseline (985.052 us; speedup 1.0000x reference)
//
#include <hip/hip_runtime.h>

#define N 512
#define NB 8

// One thread per LR pixel. All 12 passes (3 tables x 4 rotations) accumulate
// into the same 2x2 output block at (2y, 2x) -- rotations are pure coordinate
// algebra because the image is square (H == W == 512).
template <int R>
__device__ __forceinline__ void do_pass(
    const int* __restrict__ imgb, const float4* __restrict__ wt,
    int y, int x, int a, int rb, int cb, int rc, int cc,
    float& a00, float& a01, float& a10, float& a11)
{
    int by, bx, cy, cx;
    if constexpr (R == 0) {
        by = min(y + rb, N - 1); bx = min(x + cb, N - 1);
        cy = min(y + rc, N - 1); cx = min(x + cc, N - 1);
    } else if constexpr (R == 1) {
        by = min(y + cb, N - 1); bx = max(x - rb, 0);
        cy = min(y + cc, N - 1); cx = max(x - rc, 0);
    } else if constexpr (R == 2) {
        by = max(y - rb, 0);     bx = max(x - cb, 0);
        cy = max(y - rc, 0);     cx = max(x - cc, 0);
    } else {
        by = max(y - cb, 0);     bx = min(x + rb, N - 1);
        cy = max(y - cc, 0);     cx = min(x + rc, N - 1);
    }
    int pb = imgb[by * N + bx];
    int pc = imgb[cy * N + cx];
    int idx = a * 65536 + pb * 256 + pc;
    float4 w = wt[idx];
    if constexpr (R == 0) {
        a00 += w.x; a01 += w.y; a10 += w.z; a11 += w.w;
    } else if constexpr (R == 1) {
        a01 += w.x; a11 += w.y; a00 += w.z; a10 += w.w;
    } else if constexpr (R == 2) {
        a11 += w.x; a10 += w.y; a01 += w.z; a00 += w.w;
    } else {
        a10 += w.x; a00 += w.y; a11 += w.z; a01 += w.w;
    }
}

template <int R>
__device__ __forceinline__ void do_rot(
    const int* __restrict__ imgb,
    const float4* __restrict__ hw, const float4* __restrict__ dw,
    const float4* __restrict__ bw,
    int y, int x, int a,
    float& a00, float& a01, float& a10, float& a11)
{
    do_pass<R>(imgb, hw, y, x, a, 0, 1, 0, 2, a00, a01, a10, a11);  // 'h'
    do_pass<R>(imgb, dw, y, x, a, 1, 1, 2, 2, a00, a01, a10, a11);  // 'd'
    do_pass<R>(imgb, bw, y, x, a, 1, 2, 2, 1, a00, a01, a10, a11);  // 'b'
}

__global__ __launch_bounds__(256) void hdb_lut_kernel(
    const int* __restrict__ img,
    const float4* __restrict__ hw, const float4* __restrict__ dw,
    const float4* __restrict__ bw,
    float* __restrict__ out)
{
    int tid = blockIdx.x * 256 + threadIdx.x;
    int x = tid & (N - 1);
    int y = (tid >> 9) & (N - 1);
    int b = tid >> 18;

    const int* imgb = img + b * (N * N);
    int a = imgb[y * N + x];

    float a00 = 0.f, a01 = 0.f, a10 = 0.f, a11 = 0.f;

    do_rot<0>(imgb, hw, dw, bw, y, x, a, a00, a01, a10, a11);
    do_rot<1>(imgb, hw, dw, bw, y, x, a, a00, a01, a10, a11);
    do_rot<2>(imgb, hw, dw, bw, y, x, a, a00, a01, a10, a11);
    do_rot<3>(imgb, hw, dw, bw, y, x, a, a00, a01, a10, a11);

    const float s = 1.0f / 3.0f;
    size_t obase = (size_t)b * (2 * N) * (2 * N) + (size_t)(2 * y) * (2 * N) + 2 * x;
    float2* r0 = reinterpret_cast<float2*>(out + obase);
    float2* r1 = reinterpret_cast<float2*>(out + obase + 2 * N);
    *r0 = make_float2(a00 * s, a01 * s);
    *r1 = make_float2(a10 * s, a11 * s);
}

extern "C" void kernel_launch(void* const* d_in, const int* in_sizes, int n_in,
                              void* d_out, int out_size, void* d_ws, size_t ws_size,
                              hipStream_t stream) {
    const int*    img = (const int*)d_in[0];
    const float4* hw  = (const float4*)d_in[1];
    const float4* dw  = (const float4*)d_in[2];
    const float4* bw  = (const float4*)d_in[3];
    float*        out = (float*)d_out;

    const int total = NB * N * N;          // 2,097,152 threads
    const int block = 256;
    const int grid  = total / block;       // 8192 blocks
    hdb_lut_kernel<<<grid, block, 0, stream>>>(img, hw, dw, bw, out);
}